// Round 3
// baseline (1324.155 us; speedup 1.0000x reference)
//
#include <hip/hip_runtime.h>
#include <hip/hip_bf16.h>

#define T_TOK 8192
#define D_DIM 1024
#define E_NUM 16
#define I_DIM 2048
#define K_TOP 4
#define NPAIR (T_TOK * K_TOP)

typedef float f32x4 __attribute__((ext_vector_type(4)));
typedef __bf16 bf16x8 __attribute__((ext_vector_type(8)));
typedef unsigned short ushort8_t __attribute__((ext_vector_type(8)));

// ---------------- workspace layout (bytes) ----------------
#define WS_X    0ull
#define WS_W13  (WS_X    + (size_t)T_TOK * D_DIM * 2)            // x bf16: 16 MiB
#define WS_W2   (WS_W13  + (size_t)E_NUM * 2 * I_DIM * D_DIM * 2) // w13 bf16: 128 MiB
#define WS_H    (WS_W2   + (size_t)E_NUM * D_DIM * I_DIM * 2)     // w2 bf16: 64 MiB
#define WS_TKID (WS_H    + (size_t)NPAIR * I_DIM * 2)             // h bf16: 128 MiB
#define WS_TKW  (WS_TKID + (size_t)T_TOK * K_TOP * 4)
#define WS_PTOK (WS_TKW  + (size_t)T_TOK * K_TOP * 4)
#define WS_PW   (WS_PTOK + (size_t)NPAIR * 4)
#define WS_META (WS_PW   + (size_t)NPAIR * 4)
// META ints: cnt[16], cur[16], off[16]

__device__ inline unsigned short f2bf(float f) {
    unsigned u = __builtin_bit_cast(unsigned, f);
    u += 0x7fffu + ((u >> 16) & 1u);   // round-to-nearest-even
    return (unsigned short)(u >> 16);
}

// ---------------- fp32 -> bf16 conversion ----------------
__global__ void cvt_kernel(const float* __restrict__ in,
                           unsigned short* __restrict__ out, int n) {
    int idx = blockIdx.x * blockDim.x + threadIdx.x;
    int stride = gridDim.x * blockDim.x;
    for (int i = idx * 4; i < n; i += stride * 4) {
        float4 v = *(const float4*)(in + i);
        ushort4 o;
        o.x = f2bf(v.x); o.y = f2bf(v.y); o.z = f2bf(v.z); o.w = f2bf(v.w);
        *(ushort4*)(out + i) = o;
    }
}

// ---------------- router: top-4 softmax ----------------
__global__ void router_kernel(const float* __restrict__ logits,
                              int* __restrict__ tk_id, float* __restrict__ tk_w,
                              int* __restrict__ cnt) {
    int t = blockIdx.x * blockDim.x + threadIdx.x;
    if (t >= T_TOK) return;
    float l[E_NUM];
    const float4* lp = (const float4*)(logits + (size_t)t * E_NUM);
#pragma unroll
    for (int i = 0; i < 4; i++) {
        float4 v = lp[i];
        l[4 * i] = v.x; l[4 * i + 1] = v.y; l[4 * i + 2] = v.z; l[4 * i + 3] = v.w;
    }
    unsigned used = 0;
    int ids[K_TOP]; float vs[K_TOP];
#pragma unroll
    for (int k = 0; k < K_TOP; k++) {
        float best = -1e30f; int bi = 0;
#pragma unroll
        for (int e = 0; e < E_NUM; e++) {
            bool ok = !((used >> e) & 1u);
            if (ok && l[e] > best) { best = l[e]; bi = e; }
        }
        ids[k] = bi; vs[k] = best; used |= (1u << bi);
    }
    float m = vs[0];   // max of selected == global max
    float s = 0.f;
#pragma unroll
    for (int k = 0; k < K_TOP; k++) { vs[k] = expf(vs[k] - m); s += vs[k]; }
    float inv = 1.f / s;
#pragma unroll
    for (int k = 0; k < K_TOP; k++) {
        tk_id[t * K_TOP + k] = ids[k];
        tk_w[t * K_TOP + k] = vs[k] * inv;
        atomicAdd(&cnt[ids[k]], 1);
    }
}

// ---------------- offsets: exclusive prefix over 16 counts ----------------
__global__ void offsets_kernel(const int* __restrict__ cnt,
                               int* __restrict__ off, int* __restrict__ cur) {
    if (threadIdx.x == 0 && blockIdx.x == 0) {
        int o = 0;
        for (int e = 0; e < E_NUM; e++) { off[e] = o; cur[e] = o; o += cnt[e]; }
    }
}

// ---------------- scatter tokens into expert buckets ----------------
__global__ void scatter_kernel(const int* __restrict__ tk_id,
                               const float* __restrict__ tk_w,
                               int* __restrict__ cur,
                               int* __restrict__ p_tok, float* __restrict__ p_w) {
    int t = blockIdx.x * blockDim.x + threadIdx.x;
    if (t >= T_TOK) return;
#pragma unroll
    for (int k = 0; k < K_TOP; k++) {
        int e = tk_id[t * K_TOP + k];
        int pos = atomicAdd(&cur[e], 1);
        p_tok[pos] = t;
        p_w[pos] = tk_w[t * K_TOP + k];
    }
}

// ---------------- GEMM1: h = silu(x*w13g^T) * (x*w13u^T), gathered rows ----------------
__global__ __launch_bounds__(256, 2) void gemm1_kernel(
    const unsigned short* __restrict__ xb, const unsigned short* __restrict__ w13,
    const int* __restrict__ cnt, const int* __restrict__ off,
    const int* __restrict__ p_tok, unsigned short* __restrict__ h) {
    int e = blockIdx.z;
    int cnt_e = cnt[e];
    int m0 = blockIdx.y * 128;
    if (m0 >= cnt_e) return;
    int n0 = blockIdx.x * 128;
    int base = off[e];

    __shared__ unsigned short As[128][40];
    __shared__ unsigned short Bg[128][40];
    __shared__ unsigned short Bu[128][40];
    __shared__ int toks[128];

    int tid = threadIdx.x;
    int lane = tid & 63, wid = tid >> 6;
    int wm = wid >> 1, wn = wid & 1;

    if (tid < 128) {
        int r = m0 + tid;
        toks[tid] = (r < cnt_e) ? p_tok[base + r] : -1;
    }
    __syncthreads();

    int sr = tid >> 1;          // staged row 0..127
    int sc = (tid & 1) * 16;    // staged col 0 or 16
    int atok = toks[sr];
    const unsigned short* w13e = w13 + (size_t)e * (2 * I_DIM) * D_DIM;
    const unsigned short* gRow = w13e + (size_t)(n0 + sr) * D_DIM;
    const unsigned short* uRow = w13e + (size_t)(I_DIM + n0 + sr) * D_DIM;
    const unsigned short* aRow = (atok >= 0) ? (xb + (size_t)atok * D_DIM) : (const unsigned short*)0;

    f32x4 accg[4][4], accu[4][4];
#pragma unroll
    for (int m = 0; m < 4; m++)
#pragma unroll
        for (int n = 0; n < 4; n++) {
            accg[m][n] = (f32x4){0.f, 0.f, 0.f, 0.f};
            accu[m][n] = (f32x4){0.f, 0.f, 0.f, 0.f};
        }

    for (int k0 = 0; k0 < D_DIM; k0 += 32) {
        ushort8_t av0 = {0,0,0,0,0,0,0,0}, av1 = {0,0,0,0,0,0,0,0};
        if (aRow) {
            av0 = *(const ushort8_t*)(aRow + k0 + sc);
            av1 = *(const ushort8_t*)(aRow + k0 + sc + 8);
        }
        ushort8_t g0 = *(const ushort8_t*)(gRow + k0 + sc);
        ushort8_t g1 = *(const ushort8_t*)(gRow + k0 + sc + 8);
        ushort8_t u0 = *(const ushort8_t*)(uRow + k0 + sc);
        ushort8_t u1 = *(const ushort8_t*)(uRow + k0 + sc + 8);
        *(ushort8_t*)&As[sr][sc]     = av0;
        *(ushort8_t*)&As[sr][sc + 8] = av1;
        *(ushort8_t*)&Bg[sr][sc]     = g0;
        *(ushort8_t*)&Bg[sr][sc + 8] = g1;
        *(ushort8_t*)&Bu[sr][sc]     = u0;
        *(ushort8_t*)&Bu[sr][sc + 8] = u1;
        __syncthreads();

        int fr = lane & 15, fk = (lane >> 4) * 8;
        bf16x8 a[4], bg[4], bu[4];
#pragma unroll
        for (int m = 0; m < 4; m++) a[m] = *(const bf16x8*)&As[wm * 64 + m * 16 + fr][fk];
#pragma unroll
        for (int n = 0; n < 4; n++) {
            bg[n] = *(const bf16x8*)&Bg[wn * 64 + n * 16 + fr][fk];
            bu[n] = *(const bf16x8*)&Bu[wn * 64 + n * 16 + fr][fk];
        }
#pragma unroll
        for (int m = 0; m < 4; m++)
#pragma unroll
            for (int n = 0; n < 4; n++) {
                accg[m][n] = __builtin_amdgcn_mfma_f32_16x16x32_bf16(a[m], bg[n], accg[m][n], 0, 0, 0);
                accu[m][n] = __builtin_amdgcn_mfma_f32_16x16x32_bf16(a[m], bu[n], accu[m][n], 0, 0, 0);
            }
        __syncthreads();
    }

    // epilogue: h = silu(g)*u, bf16
    int fr = lane & 15, fq = lane >> 4;
#pragma unroll
    for (int m = 0; m < 4; m++) {
#pragma unroll
        for (int j = 0; j < 4; j++) {
            int rr = wm * 64 + m * 16 + fq * 4 + j;
            if (m0 + rr < cnt_e) {
                size_t hrow = (size_t)(base + m0 + rr) * I_DIM;
#pragma unroll
                for (int n = 0; n < 4; n++) {
                    float g = accg[m][n][j];
                    float u = accu[m][n][j];
                    float hh = (g / (1.f + __expf(-g))) * u;
                    h[hrow + n0 + wn * 64 + n * 16 + fr] = f2bf(hh);
                }
            }
        }
    }
}

// ---------------- GEMM2: out += pw * (h * w2^T), atomic accumulate ----------------
__global__ __launch_bounds__(256, 2) void gemm2_kernel(
    const unsigned short* __restrict__ h, const unsigned short* __restrict__ w2,
    const int* __restrict__ cnt, const int* __restrict__ off,
    const int* __restrict__ p_tok, const float* __restrict__ p_w,
    float* __restrict__ out) {
    int e = blockIdx.z;
    int cnt_e = cnt[e];
    int m0 = blockIdx.y * 128;
    if (m0 >= cnt_e) return;
    int n0 = blockIdx.x * 128;
    int base = off[e];

    __shared__ unsigned short As[128][40];
    __shared__ unsigned short Bs[128][40];
    __shared__ int toks[128];
    __shared__ float pws[128];

    int tid = threadIdx.x;
    int lane = tid & 63, wid = tid >> 6;
    int wm = wid >> 1, wn = wid & 1;

    if (tid < 128) {
        int r = m0 + tid;
        toks[tid] = (r < cnt_e) ? p_tok[base + r] : 0;
        pws[tid]  = (r < cnt_e) ? p_w[base + r] : 0.f;
    }
    __syncthreads();

    int sr = tid >> 1;
    int sc = (tid & 1) * 16;
    bool arow_ok = (m0 + sr) < cnt_e;
    const unsigned short* aRow = h + (size_t)(base + m0 + sr) * I_DIM;
    const unsigned short* bRow = w2 + (size_t)e * D_DIM * I_DIM + (size_t)(n0 + sr) * I_DIM;

    f32x4 acc[4][4];
#pragma unroll
    for (int m = 0; m < 4; m++)
#pragma unroll
        for (int n = 0; n < 4; n++) acc[m][n] = (f32x4){0.f, 0.f, 0.f, 0.f};

    for (int k0 = 0; k0 < I_DIM; k0 += 32) {
        ushort8_t a0 = {0,0,0,0,0,0,0,0}, a1 = {0,0,0,0,0,0,0,0};
        if (arow_ok) {
            a0 = *(const ushort8_t*)(aRow + k0 + sc);
            a1 = *(const ushort8_t*)(aRow + k0 + sc + 8);
        }
        ushort8_t b0 = *(const ushort8_t*)(bRow + k0 + sc);
        ushort8_t b1 = *(const ushort8_t*)(bRow + k0 + sc + 8);
        *(ushort8_t*)&As[sr][sc]     = a0;
        *(ushort8_t*)&As[sr][sc + 8] = a1;
        *(ushort8_t*)&Bs[sr][sc]     = b0;
        *(ushort8_t*)&Bs[sr][sc + 8] = b1;
        __syncthreads();

        int fr = lane & 15, fk = (lane >> 4) * 8;
        bf16x8 a[4], b[4];
#pragma unroll
        for (int m = 0; m < 4; m++) a[m] = *(const bf16x8*)&As[wm * 64 + m * 16 + fr][fk];
#pragma unroll
        for (int n = 0; n < 4; n++) b[n] = *(const bf16x8*)&Bs[wn * 64 + n * 16 + fr][fk];
#pragma unroll
        for (int m = 0; m < 4; m++)
#pragma unroll
            for (int n = 0; n < 4; n++)
                acc[m][n] = __builtin_amdgcn_mfma_f32_16x16x32_bf16(a[m], b[n], acc[m][n], 0, 0, 0);
        __syncthreads();
    }

    int fr = lane & 15, fq = lane >> 4;
#pragma unroll
    for (int m = 0; m < 4; m++) {
#pragma unroll
        for (int j = 0; j < 4; j++) {
            int rr = wm * 64 + m * 16 + fq * 4 + j;
            if (m0 + rr < cnt_e) {
                int t = toks[rr];
                float w = pws[rr];
#pragma unroll
                for (int n = 0; n < 4; n++) {
                    atomicAdd(&out[(size_t)t * D_DIM + n0 + wn * 64 + n * 16 + fr],
                              acc[m][n][j] * w);
                }
            }
        }
    }
}

// ---------------- launch ----------------
extern "C" void kernel_launch(void* const* d_in, const int* in_sizes, int n_in,
                              void* d_out, int out_size, void* d_ws, size_t ws_size,
                              hipStream_t stream) {
    const float* x      = (const float*)d_in[0];
    const float* logits = (const float*)d_in[1];
    const float* w13    = (const float*)d_in[2];
    const float* w2     = (const float*)d_in[3];
    float* out = (float*)d_out;
    char* ws = (char*)d_ws;

    unsigned short* xb   = (unsigned short*)(ws + WS_X);
    unsigned short* w13b = (unsigned short*)(ws + WS_W13);
    unsigned short* w2b  = (unsigned short*)(ws + WS_W2);
    unsigned short* hbuf = (unsigned short*)(ws + WS_H);
    int*   tk_id = (int*)(ws + WS_TKID);
    float* tk_w  = (float*)(ws + WS_TKW);
    int*   p_tok = (int*)(ws + WS_PTOK);
    float* p_w   = (float*)(ws + WS_PW);
    int* meta = (int*)(ws + WS_META);
    int* cnt = meta;
    int* cur = meta + 16;
    int* off = meta + 32;

    hipMemsetAsync(meta, 0, 32 * sizeof(int), stream);
    hipMemsetAsync(out, 0, (size_t)T_TOK * D_DIM * sizeof(float), stream);

    cvt_kernel<<<1024, 256, 0, stream>>>(x, xb, T_TOK * D_DIM);
    cvt_kernel<<<2048, 256, 0, stream>>>(w13, w13b, E_NUM * 2 * I_DIM * D_DIM);
    cvt_kernel<<<2048, 256, 0, stream>>>(w2, w2b, E_NUM * D_DIM * I_DIM);

    router_kernel<<<T_TOK / 256, 256, 0, stream>>>(logits, tk_id, tk_w, cnt);
    offsets_kernel<<<1, 64, 0, stream>>>(cnt, off, cur);
    scatter_kernel<<<T_TOK / 256, 256, 0, stream>>>(tk_id, tk_w, cur, p_tok, p_w);

    dim3 g1(I_DIM / 128, 64, E_NUM);
    gemm1_kernel<<<g1, 256, 0, stream>>>(xb, w13b, cnt, off, p_tok, hbuf);
    dim3 g2(D_DIM / 128, 64, E_NUM);
    gemm2_kernel<<<g2, 256, 0, stream>>>(hbuf, w2b, cnt, off, p_tok, p_w, out);
}